// Round 4
// baseline (36.357 us; speedup 1.0000x reference)
//
#include <hip/hip_runtime.h>

// NeRF volume rendering, 8 samples per lane, 16 lanes per ray, 4 rays/wave.
// R3 = R2 with compile fix: nontemporal stores use a clang ext_vector float4
// (HIP_vector_type is rejected by __builtin_nontemporal_store).

typedef float vfloat4 __attribute__((ext_vector_type(4)));

#define CEX(a,b) { float mn_=fminf(v[a],v[b]); v[b]=fmaxf(v[a],v[b]); v[a]=mn_; }

// first pass of merge S->2S: partner = reversed regs
#define CROSS_REV(mask, lowbit) { \
  float w_[8]; \
  _Pragma("unroll") for (int r_=0;r_<8;++r_) w_[r_]=__shfl_xor(v[7-r_], (mask)); \
  const bool lo_ = (gl & (lowbit)) == 0; \
  _Pragma("unroll") for (int r_=0;r_<8;++r_) \
    v[r_] = lo_ ? fminf(v[r_],w_[r_]) : fmaxf(v[r_],w_[r_]); }

// uniform-ascending cross-lane CE pass
#define CROSS(mask, lowbit) { \
  float w_[8]; \
  _Pragma("unroll") for (int r_=0;r_<8;++r_) w_[r_]=__shfl_xor(v[r_], (mask)); \
  const bool lo_ = (gl & (lowbit)) == 0; \
  _Pragma("unroll") for (int r_=0;r_<8;++r_) \
    v[r_] = lo_ ? fminf(v[r_],w_[r_]) : fmaxf(v[r_],w_[r_]); }

// in-lane ascending bitonic merge of 8 (strides 4,2,1)
#define INLANE8() { CEX(0,4) CEX(1,5) CEX(2,6) CEX(3,7) \
                    CEX(0,2) CEX(1,3) CEX(4,6) CEX(5,7) \
                    CEX(0,1) CEX(2,3) CEX(4,5) CEX(6,7) }

__global__ __launch_bounds__(256, 8) void nerf_render_kernel(
    const float* __restrict__ t,
    const float* __restrict__ sigma,
    const float* __restrict__ c,
    float* __restrict__ out,
    int n_rays) {
  const int tid  = threadIdx.x;
  const int lane = tid & 63;
  const int gl   = lane & 15;               // lane within the 16-lane ray group
  const int ray  = blockIdx.x * 16 + (tid >> 4);
  if (ray >= n_rays) return;

  // ---- issue ALL input loads up front (latency overlaps the sort) ----
  const float4* tb = (const float4*)(t     + (size_t)ray * 128 + gl * 8);
  const float4* sb = (const float4*)(sigma + (size_t)ray * 128 + gl * 8);
  const float4* cb = (const float4*)(c     + (size_t)ray * 384 + gl * 24);
  const float4 tA = tb[0], tB = tb[1];
  const float4 sA = sb[0], sB = sb[1];
  float carr[24];
#pragma unroll
  for (int q = 0; q < 6; ++q) *(float4*)&carr[q * 4] = cb[q];

  float v[8];
  v[0]=tA.x; v[1]=tA.y; v[2]=tA.z; v[3]=tA.w;
  v[4]=tB.x; v[5]=tB.y; v[6]=tB.z; v[7]=tB.w;

  // ---- in-lane Batcher odd-even mergesort of 8 (ascending, 19 CEs) ----
  CEX(0,1) CEX(2,3) CEX(4,5) CEX(6,7)
  CEX(0,2) CEX(1,3) CEX(4,6) CEX(5,7)
  CEX(1,2) CEX(5,6)
  CEX(0,4) CEX(1,5) CEX(2,6) CEX(3,7)
  CEX(2,4) CEX(3,5)
  CEX(1,2) CEX(3,4) CEX(5,6)

  // ---- merge 8->16 / 16->32 / 32->64 / 64->128 ----
  CROSS_REV(1, 1)  INLANE8()
  CROSS_REV(3, 2)  CROSS(1, 1)  INLANE8()
  CROSS_REV(7, 4)  CROSS(2, 2)  CROSS(1, 1)  INLANE8()
  CROSS_REV(15, 8) CROSS(4, 4)  CROSS(2, 2)  CROSS(1, 1)  INLANE8()

  // ---- dt (last sample of ray gets dt = 0) ----
  const float nxt = __shfl(v[0], (lane + 1) & 63);
  float dt[8];
#pragma unroll
  for (int r = 0; r < 7; ++r) dt[r] = v[r + 1] - v[r];
  dt[7] = (gl == 15) ? 0.0f : (nxt - v[7]);

  // ---- sigma * dt ----
  float sdt[8];
  sdt[0]=sA.x*dt[0]; sdt[1]=sA.y*dt[1]; sdt[2]=sA.z*dt[2]; sdt[3]=sA.w*dt[3];
  sdt[4]=sB.x*dt[4]; sdt[5]=sB.y*dt[5]; sdt[6]=sB.z*dt[6]; sdt[7]=sB.w*dt[7];

  // ---- prefix sums: in-lane inclusive, then 16-lane exclusive scan ----
  float p[8];
  p[0] = sdt[0];
#pragma unroll
  for (int r = 1; r < 8; ++r) p[r] = p[r - 1] + sdt[r];
  float s = p[7];
#pragma unroll
  for (int off = 1; off < 16; off <<= 1) {
    const float u = __shfl_up(s, off);
    if (gl >= off) s += u;
  }
  const float excl = s - p[7];   // sum of all sdt before this lane's 8 samples

  // ---- weights: wi_i = exp(-cum_excl_i) - exp(-cum_incl_i) ----
  float wi[8];
  float Eprev = __expf(-excl);
#pragma unroll
  for (int r = 0; r < 8; ++r) {
    const float Er = __expf(-(excl + p[r]));
    wi[r] = Eprev - Er;
    Eprev = Er;
  }

  // ---- color / depth partials ----
  float pr = 0.f, pg = 0.f, pb = 0.f, pd = 0.f;
#pragma unroll
  for (int r = 0; r < 8; ++r) {
    pr += wi[r] * carr[3 * r + 0];
    pg += wi[r] * carr[3 * r + 1];
    pb += wi[r] * carr[3 * r + 2];
    pd += wi[r] * v[r];
  }

  // ---- 16-lane butterfly reduction ----
#pragma unroll
  for (int m = 8; m >= 1; m >>= 1) {
    pr += __shfl_xor(pr, m);
    pg += __shfl_xor(pg, m);
    pb += __shfl_xor(pb, m);
    pd += __shfl_xor(pd, m);
  }

  // ---- stores (non-temporal): out = color [N*3] | depth [N] | wi [N*128] ----
  float* wo = out + (size_t)n_rays * 4 + (size_t)ray * 128 + gl * 8;
  vfloat4 w03 = { wi[0], wi[1], wi[2], wi[3] };
  vfloat4 w47 = { wi[4], wi[5], wi[6], wi[7] };
  __builtin_nontemporal_store(w03, (vfloat4*)wo);
  __builtin_nontemporal_store(w47, (vfloat4*)(wo + 4));
  if (gl == 0) {
    __builtin_nontemporal_store(pr, &out[(size_t)ray * 3 + 0]);
    __builtin_nontemporal_store(pg, &out[(size_t)ray * 3 + 1]);
    __builtin_nontemporal_store(pb, &out[(size_t)ray * 3 + 2]);
    __builtin_nontemporal_store(pd, &out[(size_t)n_rays * 3 + ray]);
  }
}

extern "C" void kernel_launch(void* const* d_in, const int* in_sizes, int n_in,
                              void* d_out, int out_size, void* d_ws, size_t ws_size,
                              hipStream_t stream) {
  const float* t     = (const float*)d_in[0];
  const float* sigma = (const float*)d_in[1];
  const float* c     = (const float*)d_in[2];
  float* out = (float*)d_out;
  const int n_rays = in_sizes[0] / 128;
  const int blocks = (n_rays + 15) / 16;   // 16 rays per 256-thread block
  nerf_render_kernel<<<blocks, 256, 0, stream>>>(t, sigma, c, out, n_rays);
}